// Round 15
// baseline (156.257 us; speedup 1.0000x reference)
//
#include <hip/hip_runtime.h>
#include <math.h>

#define EPS32   1e-8f                 // f32(1e-8) — matches numpy NEP50 weak-scalar
#define INV4PI  0.07957747154594767f
#define TPB     256
#define TPB_F   64    // face_k block size (spread 16K faces over 256 blocks)
#define VSLICE  64    // vertices per y-slice
#define PPT     16    // points per thread (register-blocked)

// ---------------------------------------------------------------- zero init (2 bufs, 1 launch)
__global__ void zero2_k(float* __restrict__ a, int na,
                        float* __restrict__ b, int nb) {
    int i = blockIdx.x * TPB + threadIdx.x;
    if (i < na) a[i] = 0.0f;
    else if (i < na + nb) b[i - na] = 0.0f;
}

// f32 norm with numpy's summation order: sqrt((x^2 + y^2) + z^2), each op
// individually rounded (no FMA contraction — *_rn intrinsics are never fused).
__device__ __forceinline__ float n3_f32(float x, float y, float z) {
    return __fsqrt_rn(__fadd_rn(__fadd_rn(__fmul_rn(x, x), __fmul_rn(y, y)),
                                __fmul_rn(z, z)));
}

// ---------------------------------------------------------------- per-face
// Bit-exact f32 mirror of the numpy reference's corner-angle weight pipeline.
// DO NOT "improve" the math here: the output is ill-conditioned through
// near-collinear faces whose weights are set by f32 storage rounding (r5
// exact-identity f32 -> absmax 593; r7 fp64 truth -> 433; r8 this mirror ->
// 56 PASS). theta/sin via f64-then-round = correctly-rounded f32 ~ glibc.
__global__ void face_k(const float* __restrict__ verts,
                       const int*   __restrict__ faces,
                       float*       __restrict__ acc, int F) {
    int f = blockIdx.x * TPB_F + threadIdx.x;
    if (f >= F) return;
    int i0 = faces[3*f+0], i1 = faces[3*f+1], i2 = faces[3*f+2];
    float p0x = verts[3*i0], p0y = verts[3*i0+1], p0z = verts[3*i0+2];
    float p1x = verts[3*i1], p1y = verts[3*i1+1], p1z = verts[3*i1+2];
    float p2x = verts[3*i2], p2y = verts[3*i2+1], p2z = verts[3*i2+2];

    float Ax = __fsub_rn(p1x, p0x), Ay = __fsub_rn(p1y, p0y), Az = __fsub_rn(p1z, p0z);
    float Bx = __fsub_rn(p2x, p1x), By = __fsub_rn(p2y, p1y), Bz = __fsub_rn(p2z, p1z);
    float Cx = __fsub_rn(p0x, p2x), Cy = __fsub_rn(p0y, p2y), Cz = __fsub_rn(p0z, p2z);

    float nA = n3_f32(Ax, Ay, Az);
    float nB = n3_f32(Bx, By, Bz);
    float nC = n3_f32(Cx, Cy, Cz);

    // corner_angle(u,v): c = -sum(u*v)/(EPS + |u||v|), clip, acos; s2 = sin(2*theta)
    auto s2f = [](float ux, float uy, float uz, float vx, float vy, float vz,
                  float nu, float nv) {
        float d   = __fadd_rn(__fadd_rn(__fmul_rn(ux, vx), __fmul_rn(uy, vy)),
                              __fmul_rn(uz, vz));
        float den = __fadd_rn(EPS32, __fmul_rn(nu, nv));
        float c   = __fdiv_rn(-d, den);              // IEEE f32 div == numpy
        c = fminf(1.0f, fmaxf(-1.0f, c));
        float th  = (float)acos((double)c);          // correctly-rounded f32 acos
        return (float)sin(2.0 * (double)th);         // 2*theta exact; c-r f32 sin
    };
    float s0 = s2f(Cx,Cy,Cz, Ax,Ay,Az, nC, nA);   // angle at corner 0
    float s1 = s2f(Ax,Ay,Az, Bx,By,Bz, nA, nB);   // angle at corner 1
    float s2 = s2f(Bx,By,Bz, Cx,Cy,Cz, nB, nC);   // angle at corner 2

    float ssum  = __fadd_rn(__fadd_rn(s0, s1), s2);   // numpy sum order
    float wden  = __fadd_rn(ssum, EPS32);
    float w0 = __fdiv_rn(s0, wden);
    float w1 = __fdiv_rn(s1, wden);
    float w2 = __fdiv_rn(s2, wden);

    // fn = cross(A,B); mul-mul-sub, no FMA (numpy semantics)
    float fnx = __fsub_rn(__fmul_rn(Ay, Bz), __fmul_rn(Az, By));
    float fny = __fsub_rn(__fmul_rn(Az, Bx), __fmul_rn(Ax, Bz));
    float fnz = __fsub_rn(__fmul_rn(Ax, By), __fmul_rn(Ay, Bx));
    float area = __fmul_rn(0.5f, n3_f32(fnx, fny, fnz));

    // w' = (w[[2,0,1]] + w[[1,2,0]]) / 2  (/2 is exact), then * area
    float c0 = __fmul_rn(__fmul_rn(__fadd_rn(w2, w1), 0.5f), area);
    float c1 = __fmul_rn(__fmul_rn(__fadd_rn(w0, w2), 0.5f), area);
    float c2 = __fmul_rn(__fmul_rn(__fadd_rn(w1, w0), 0.5f), area);

    atomicAdd(&acc[4*i0+0], c0);
    atomicAdd(&acc[4*i0+1], fnx); atomicAdd(&acc[4*i0+2], fny); atomicAdd(&acc[4*i0+3], fnz);
    atomicAdd(&acc[4*i1+0], c1);
    atomicAdd(&acc[4*i1+1], fnx); atomicAdd(&acc[4*i1+2], fny); atomicAdd(&acc[4*i1+3], fnz);
    atomicAdd(&acc[4*i2+0], c2);
    atomicAdd(&acc[4*i2+1], fnx); atomicAdd(&acc[4*i2+2], fny); atomicAdd(&acc[4*i2+3], fnz);
}

// ---------------------------------------------------------------- main pass (fp32)
// r14 structure with PPT 8->16: each staged vertex pair now feeds 32
// interactions (ds_read+loop overhead halves to ~1.5 cyc/interaction),
// out-atomics halve, 32 independent chains/j-iter cover the
// sqrt->fma->rcp latency. Inner body STRAIGHT-LINE (r12/r13: any branch
// regresses 30-40%). Exact eps sequence (sqrt -> fma(r,r2,eps) -> rcp)
// is semantically forced: min-pair r^3 ~ eps, term ~2e4, budget ~70.
__global__ __launch_bounds__(TPB) void wind_k(const float* __restrict__ points,
                                              const float* __restrict__ verts,
                                              const float* __restrict__ acc,
                                              float*       __restrict__ out,
                                              int P, int V) {
    __shared__ float sv[VSLICE*6];
    const int vbase = blockIdx.y * VSLICE;
    const int nv    = min(VSLICE, V - vbase);

    {   // vert prologue (former vert_k, per-op identical)
        int i = threadIdx.x;
        if (i < nv) {
            int v = vbase + i;
            float dual = acc[4*v+0];
            float nx = acc[4*v+1], ny = acc[4*v+2], nz = acc[4*v+3];
            float den = __fadd_rn(n3_f32(nx, ny, nz), EPS32);
            float sx = __fmul_rn(__fdiv_rn(nx, den), dual);
            float sy = __fmul_rn(__fdiv_rn(ny, den), dual);
            float sz = __fmul_rn(__fdiv_rn(nz, den), dual);
            sv[6*i+0] = verts[3*v+0];
            sv[6*i+1] = verts[3*v+1];
            sv[6*i+2] = verts[3*v+2];
            sv[6*i+3] = __fmul_rn(sx, INV4PI);
            sv[6*i+4] = __fmul_rn(sy, INV4PI);
            sv[6*i+5] = __fmul_rn(sz, INV4PI);
        }
    }
    __syncthreads();

    const int pb = blockIdx.x * (TPB*PPT) + threadIdx.x;
    float px[PPT], py[PPT], pz[PPT], accp[PPT];
    bool  ok[PPT];
#pragma unroll
    for (int k = 0; k < PPT; ++k) {
        int p = pb + k*TPB;
        ok[k] = p < P;
        px[k] = ok[k] ? points[3*p+0] : 0.f;
        py[k] = ok[k] ? points[3*p+1] : 0.f;
        pz[k] = ok[k] ? points[3*p+2] : 0.f;
        accp[k] = 0.0f;
    }

    // term = (na . (v-p)) / (r^3 + eps); raw v_sqrt_f32 + raw v_rcp_f32
    // (<=1 ulp each): per-term rel err ~2.4e-7, unamplified.
    auto interact = [](float vx, float vy, float vz,
                       float nx, float ny, float nz,
                       float qx, float qy, float qz, float& a) {
        float dx = vx - qx, dy = vy - qy, dz = vz - qz;
        float r2 = fmaf(dx, dx, fmaf(dy, dy, dz*dz));
        float r  = __builtin_amdgcn_sqrtf(r2);
        float denom = fmaf(r, r2, EPS32);              // r^3 + eps (ref semantics)
        float num   = fmaf(dx, nx, fmaf(dy, ny, dz*nz));
        a = fmaf(num, __builtin_amdgcn_rcpf(denom), a);
    };

    const float4* s4 = (const float4*)sv;
    const int npair = nv >> 1;
#pragma unroll 2
    for (int j = 0; j < npair; ++j) {
        // 3 x ds_read_b128, wave-uniform (broadcast, conflict-free)
        float4 A = s4[3*j+0];   // v0x v0y v0z | n0x
        float4 B = s4[3*j+1];   // n0y n0z v1x | v1y
        float4 C = s4[3*j+2];   // v1z n1x n1y | n1z
#pragma unroll
        for (int k = 0; k < PPT; ++k)
            interact(A.x,A.y,A.z, A.w,B.x,B.y, px[k],py[k],pz[k], accp[k]);
#pragma unroll
        for (int k = 0; k < PPT; ++k)
            interact(B.z,B.w,C.x, C.y,C.z,C.w, px[k],py[k],pz[k], accp[k]);
    }
    if (nv & 1) {                                       // generic tail (unused at V=8192)
        int i = nv - 1;
#pragma unroll
        for (int k = 0; k < PPT; ++k)
            interact(sv[6*i],sv[6*i+1],sv[6*i+2], sv[6*i+3],sv[6*i+4],sv[6*i+5],
                     px[k],py[k],pz[k], accp[k]);
    }

#pragma unroll
    for (int k = 0; k < PPT; ++k)
        if (ok[k]) atomicAdd(&out[pb + k*TPB], accp[k]);
}

// ---------------------------------------------------------------- launch
extern "C" void kernel_launch(void* const* d_in, const int* in_sizes, int n_in,
                              void* d_out, int out_size, void* d_ws, size_t ws_size,
                              hipStream_t stream) {
    const float* verts  = (const float*)d_in[0];
    const float* points = (const float*)d_in[1];
    const int*   faces  = (const int*)  d_in[2];
    float*       out    = (float*)d_out;

    const int V = in_sizes[0] / 3;
    const int P = in_sizes[1] / 3;
    const int F = in_sizes[2] / 3;

    // ws layout: acc = V*4 floats (128 KB)
    float* acc = (float*)d_ws;

    zero2_k<<<(P + 4*V + TPB-1)/TPB, TPB, 0, stream>>>(out, P, acc, 4*V);
    face_k<<<(F + TPB_F-1)/TPB_F, TPB_F, 0, stream>>>(verts, faces, acc, F);

    dim3 grid((P + TPB*PPT - 1)/(TPB*PPT), (V + VSLICE-1)/VSLICE);
    wind_k<<<grid, TPB, 0, stream>>>(points, verts, acc, out, P, V);
}

// Round 16
// 153.984 us; speedup vs baseline: 1.0148x; 1.0148x over previous
//
#include <hip/hip_runtime.h>
#include <math.h>

#define EPS32   1e-8f                 // f32(1e-8) — matches numpy NEP50 weak-scalar
#define INV4PI  0.07957747154594767f
#define TPB     256
#define TPB_F   64    // face_k block size (spread 16K faces over 256 blocks)
#define VSLICE  64    // vertices per y-slice
#define PPT     8     // points per thread — best measured (r14: 98.0 us)

// ---------------------------------------------------------------- zero init (2 bufs, 1 launch)
__global__ void zero2_k(float* __restrict__ a, int na,
                        float* __restrict__ b, int nb) {
    int i = blockIdx.x * TPB + threadIdx.x;
    if (i < na) a[i] = 0.0f;
    else if (i < na + nb) b[i - na] = 0.0f;
}

// f32 norm with numpy's summation order: sqrt((x^2 + y^2) + z^2), each op
// individually rounded (no FMA contraction — *_rn intrinsics are never fused).
__device__ __forceinline__ float n3_f32(float x, float y, float z) {
    return __fsqrt_rn(__fadd_rn(__fadd_rn(__fmul_rn(x, x), __fmul_rn(y, y)),
                                __fmul_rn(z, z)));
}

// ---------------------------------------------------------------- per-face
// Bit-exact f32 mirror of the numpy reference's corner-angle weight pipeline.
// DO NOT "improve" the math here: the output is ill-conditioned through
// near-collinear faces whose weights are set by f32 storage rounding (r5
// exact-identity f32 -> absmax 593; r7 fp64 truth -> 433; r8 this mirror ->
// 56 PASS). theta/sin via f64-then-round = correctly-rounded f32 ~ glibc.
__global__ void face_k(const float* __restrict__ verts,
                       const int*   __restrict__ faces,
                       float*       __restrict__ acc, int F) {
    int f = blockIdx.x * TPB_F + threadIdx.x;
    if (f >= F) return;
    int i0 = faces[3*f+0], i1 = faces[3*f+1], i2 = faces[3*f+2];
    float p0x = verts[3*i0], p0y = verts[3*i0+1], p0z = verts[3*i0+2];
    float p1x = verts[3*i1], p1y = verts[3*i1+1], p1z = verts[3*i1+2];
    float p2x = verts[3*i2], p2y = verts[3*i2+1], p2z = verts[3*i2+2];

    float Ax = __fsub_rn(p1x, p0x), Ay = __fsub_rn(p1y, p0y), Az = __fsub_rn(p1z, p0z);
    float Bx = __fsub_rn(p2x, p1x), By = __fsub_rn(p2y, p1y), Bz = __fsub_rn(p2z, p1z);
    float Cx = __fsub_rn(p0x, p2x), Cy = __fsub_rn(p0y, p2y), Cz = __fsub_rn(p0z, p2z);

    float nA = n3_f32(Ax, Ay, Az);
    float nB = n3_f32(Bx, By, Bz);
    float nC = n3_f32(Cx, Cy, Cz);

    // corner_angle(u,v): c = -sum(u*v)/(EPS + |u||v|), clip, acos; s2 = sin(2*theta)
    auto s2f = [](float ux, float uy, float uz, float vx, float vy, float vz,
                  float nu, float nv) {
        float d   = __fadd_rn(__fadd_rn(__fmul_rn(ux, vx), __fmul_rn(uy, vy)),
                              __fmul_rn(uz, vz));
        float den = __fadd_rn(EPS32, __fmul_rn(nu, nv));
        float c   = __fdiv_rn(-d, den);              // IEEE f32 div == numpy
        c = fminf(1.0f, fmaxf(-1.0f, c));
        float th  = (float)acos((double)c);          // correctly-rounded f32 acos
        return (float)sin(2.0 * (double)th);         // 2*theta exact; c-r f32 sin
    };
    float s0 = s2f(Cx,Cy,Cz, Ax,Ay,Az, nC, nA);   // angle at corner 0
    float s1 = s2f(Ax,Ay,Az, Bx,By,Bz, nA, nB);   // angle at corner 1
    float s2 = s2f(Bx,By,Bz, Cx,Cy,Cz, nB, nC);   // angle at corner 2

    float ssum  = __fadd_rn(__fadd_rn(s0, s1), s2);   // numpy sum order
    float wden  = __fadd_rn(ssum, EPS32);
    float w0 = __fdiv_rn(s0, wden);
    float w1 = __fdiv_rn(s1, wden);
    float w2 = __fdiv_rn(s2, wden);

    // fn = cross(A,B); mul-mul-sub, no FMA (numpy semantics)
    float fnx = __fsub_rn(__fmul_rn(Ay, Bz), __fmul_rn(Az, By));
    float fny = __fsub_rn(__fmul_rn(Az, Bx), __fmul_rn(Ax, Bz));
    float fnz = __fsub_rn(__fmul_rn(Ax, By), __fmul_rn(Ay, Bx));
    float area = __fmul_rn(0.5f, n3_f32(fnx, fny, fnz));

    // w' = (w[[2,0,1]] + w[[1,2,0]]) / 2  (/2 is exact), then * area
    float c0 = __fmul_rn(__fmul_rn(__fadd_rn(w2, w1), 0.5f), area);
    float c1 = __fmul_rn(__fmul_rn(__fadd_rn(w0, w2), 0.5f), area);
    float c2 = __fmul_rn(__fmul_rn(__fadd_rn(w1, w0), 0.5f), area);

    atomicAdd(&acc[4*i0+0], c0);
    atomicAdd(&acc[4*i0+1], fnx); atomicAdd(&acc[4*i0+2], fny); atomicAdd(&acc[4*i0+3], fnz);
    atomicAdd(&acc[4*i1+0], c1);
    atomicAdd(&acc[4*i1+1], fnx); atomicAdd(&acc[4*i1+2], fny); atomicAdd(&acc[4*i1+3], fnz);
    atomicAdd(&acc[4*i2+0], c2);
    atomicAdd(&acc[4*i2+1], fnx); atomicAdd(&acc[4*i2+2], fny); atomicAdd(&acc[4*i2+3], fnz);
}

// ---------------------------------------------------------------- main pass (fp32)
// FINAL config (best measured across r8-r15 sweep): PPT=8, VSLICE=64,
// float4 LDS broadcast reads, fused vert prologue, straight-line body.
// Sweep evidence: PPT {2,4,8,16} x VSLICE {64..512} x {LDS, global} all
// 98-104 us; branches (divergent r12, uniform-vote r13) regress 30-40%.
// Exact eps sequence (sqrt -> fma(r,r2,eps) -> rcp) is semantically forced:
// min-pair r^3 ~ eps, term ~2e4, abs budget ~70; |v|^2-2vp expansion loses
// ~10% rel on r2 at the near pair -> fails. 11 VALU + 2 trans = 38
// issue-cyc/wave-interaction is the structural floor; measured busy 80 us
// matches at sustained clock.
__global__ __launch_bounds__(TPB) void wind_k(const float* __restrict__ points,
                                              const float* __restrict__ verts,
                                              const float* __restrict__ acc,
                                              float*       __restrict__ out,
                                              int P, int V) {
    __shared__ float sv[VSLICE*6];
    const int vbase = blockIdx.y * VSLICE;
    const int nv    = min(VSLICE, V - vbase);

    {   // vert prologue (former vert_k, per-op identical)
        int i = threadIdx.x;
        if (i < nv) {
            int v = vbase + i;
            float dual = acc[4*v+0];
            float nx = acc[4*v+1], ny = acc[4*v+2], nz = acc[4*v+3];
            float den = __fadd_rn(n3_f32(nx, ny, nz), EPS32);
            float sx = __fmul_rn(__fdiv_rn(nx, den), dual);
            float sy = __fmul_rn(__fdiv_rn(ny, den), dual);
            float sz = __fmul_rn(__fdiv_rn(nz, den), dual);
            sv[6*i+0] = verts[3*v+0];
            sv[6*i+1] = verts[3*v+1];
            sv[6*i+2] = verts[3*v+2];
            sv[6*i+3] = __fmul_rn(sx, INV4PI);
            sv[6*i+4] = __fmul_rn(sy, INV4PI);
            sv[6*i+5] = __fmul_rn(sz, INV4PI);
        }
    }
    __syncthreads();

    const int pb = blockIdx.x * (TPB*PPT) + threadIdx.x;
    float px[PPT], py[PPT], pz[PPT], accp[PPT];
    bool  ok[PPT];
#pragma unroll
    for (int k = 0; k < PPT; ++k) {
        int p = pb + k*TPB;
        ok[k] = p < P;
        px[k] = ok[k] ? points[3*p+0] : 0.f;
        py[k] = ok[k] ? points[3*p+1] : 0.f;
        pz[k] = ok[k] ? points[3*p+2] : 0.f;
        accp[k] = 0.0f;
    }

    // term = (na . (v-p)) / (r^3 + eps); raw v_sqrt_f32 + raw v_rcp_f32
    // (<=1 ulp each): per-term rel err ~2.4e-7, unamplified.
    auto interact = [](float vx, float vy, float vz,
                       float nx, float ny, float nz,
                       float qx, float qy, float qz, float& a) {
        float dx = vx - qx, dy = vy - qy, dz = vz - qz;
        float r2 = fmaf(dx, dx, fmaf(dy, dy, dz*dz));
        float r  = __builtin_amdgcn_sqrtf(r2);
        float denom = fmaf(r, r2, EPS32);              // r^3 + eps (ref semantics)
        float num   = fmaf(dx, nx, fmaf(dy, ny, dz*nz));
        a = fmaf(num, __builtin_amdgcn_rcpf(denom), a);
    };

    const float4* s4 = (const float4*)sv;
    const int npair = nv >> 1;
#pragma unroll 4
    for (int j = 0; j < npair; ++j) {
        // 3 x ds_read_b128, wave-uniform (broadcast, conflict-free)
        float4 A = s4[3*j+0];   // v0x v0y v0z | n0x
        float4 B = s4[3*j+1];   // n0y n0z v1x | v1y
        float4 C = s4[3*j+2];   // v1z n1x n1y | n1z
#pragma unroll
        for (int k = 0; k < PPT; ++k)
            interact(A.x,A.y,A.z, A.w,B.x,B.y, px[k],py[k],pz[k], accp[k]);
#pragma unroll
        for (int k = 0; k < PPT; ++k)
            interact(B.z,B.w,C.x, C.y,C.z,C.w, px[k],py[k],pz[k], accp[k]);
    }
    if (nv & 1) {                                       // generic tail (unused at V=8192)
        int i = nv - 1;
#pragma unroll
        for (int k = 0; k < PPT; ++k)
            interact(sv[6*i],sv[6*i+1],sv[6*i+2], sv[6*i+3],sv[6*i+4],sv[6*i+5],
                     px[k],py[k],pz[k], accp[k]);
    }

#pragma unroll
    for (int k = 0; k < PPT; ++k)
        if (ok[k]) atomicAdd(&out[pb + k*TPB], accp[k]);
}

// ---------------------------------------------------------------- launch
extern "C" void kernel_launch(void* const* d_in, const int* in_sizes, int n_in,
                              void* d_out, int out_size, void* d_ws, size_t ws_size,
                              hipStream_t stream) {
    const float* verts  = (const float*)d_in[0];
    const float* points = (const float*)d_in[1];
    const int*   faces  = (const int*)  d_in[2];
    float*       out    = (float*)d_out;

    const int V = in_sizes[0] / 3;
    const int P = in_sizes[1] / 3;
    const int F = in_sizes[2] / 3;

    // ws layout: acc = V*4 floats (128 KB)
    float* acc = (float*)d_ws;

    zero2_k<<<(P + 4*V + TPB-1)/TPB, TPB, 0, stream>>>(out, P, acc, 4*V);
    face_k<<<(F + TPB_F-1)/TPB_F, TPB_F, 0, stream>>>(verts, faces, acc, F);

    dim3 grid((P + TPB*PPT - 1)/(TPB*PPT), (V + VSLICE-1)/VSLICE);
    wind_k<<<grid, TPB, 0, stream>>>(points, verts, acc, out, P, V);
}